// Round 3
// baseline (240.605 us; speedup 1.0000x reference)
//
#include <hip/hip_runtime.h>
#include <hip/hip_bf16.h>
#include <float.h>

#define B_ 1024
#define H_ 512
#define N_ (B_ * 64)
#define FFN_ 2048
#define OUT_ 86

typedef __bf16 bf16_t;
typedef __attribute__((ext_vector_type(8))) __bf16 bf16x8;
typedef __attribute__((ext_vector_type(4))) float f32x4;

__device__ __forceinline__ float wred_sum(float v) {
#pragma unroll
  for (int m = 32; m; m >>= 1) v += __shfl_xor(v, m);
  return v;
}
__device__ __forceinline__ float wred_max(float v) {
#pragma unroll
  for (int m = 32; m; m >>= 1) v = fmaxf(v, __shfl_xor(v, m));
  return v;
}

__device__ __forceinline__ void gload_lds16(const void* g, void* l) {
  __builtin_amdgcn_global_load_lds((const __attribute__((address_space(1))) unsigned int*)g,
                                   (__attribute__((address_space(3))) unsigned int*)l, 16, 0, 0);
}

#define BARRAW() do { asm volatile("s_waitcnt lgkmcnt(0)" ::: "memory"); __builtin_amdgcn_s_barrier(); } while (0)

// d[k] = sum_h w_i_w[k][h]*prj_b[h]; e[j] = sum_h prj_w[j][h]*w_b[h]; c0 = w_b . prj_b
__global__ void k_prep(const float* __restrict__ w_i_w, const float* __restrict__ w_i_b,
                       const float* __restrict__ prj_w, const float* __restrict__ prj_b,
                       float* __restrict__ dv, float* __restrict__ ev, float* __restrict__ c0) {
  int b = blockIdx.x, l = threadIdx.x;
  float s = 0.f;
  if (b < 512) {
    for (int h = l; h < H_; h += 64) s += w_i_w[b * H_ + h] * prj_b[h];
    s = wred_sum(s);
    if (l == 0) dv[b] = s;
  } else if (b < 1024) {
    int j = b - 512;
    for (int h = l; h < H_; h += 64) s += prj_w[j * H_ + h] * w_i_b[h];
    s = wred_sum(s);
    if (l == 0) ev[j] = s;
  } else {
    for (int h = l; h < H_; h += 64) s += w_i_b[h] * prj_b[h];
    s = wred_sum(s);
    if (l == 0) c0[0] = s;
  }
}

__global__ void k_cvec(const float* __restrict__ ro, const float* __restrict__ lo,
                       const float* __restrict__ ev, const float* __restrict__ c0,
                       float* __restrict__ cL, float* __restrict__ cR) {
  int b = blockIdx.x, side = blockIdx.y, l = threadIdx.x;
  const float* x = side ? lo : ro;
  float s = 0.f;
  for (int j = l; j < H_; j += 64) s += x[b * H_ + j] * ev[j];
  s = wred_sum(s);
  if (l == 0) (side ? cR : cL)[b] = s + c0[0];
}

// Generic f32 tiled GEMM (small score-path GEMMs, f32 for accuracy)
template <bool BT, bool BIAS, bool RELU>
__global__ __launch_bounds__(256) void gemm64(const float* __restrict__ A, const float* __restrict__ Bm,
                                              const float* __restrict__ bias, float* __restrict__ C,
                                              int M, int N, int K) {
  __shared__ float As[16][68];
  __shared__ float Bs[16][68];
  const int bm = blockIdx.x * 64, bn = blockIdx.y * 64;
  const int t = threadIdx.x;
  const int tx = t & 15, ty = t >> 4;
  float acc[4][4] = {};
  for (int k0 = 0; k0 < K; k0 += 16) {
#pragma unroll
    for (int i = 0; i < 4; i++) {
      int m = (t >> 4) + i * 16;
      As[t & 15][m] = A[(size_t)(bm + m) * K + k0 + (t & 15)];
    }
    if (BT) {
#pragma unroll
      for (int i = 0; i < 4; i++) {
        int n = (t >> 4) + i * 16;
        Bs[t & 15][n] = Bm[(size_t)(bn + n) * K + k0 + (t & 15)];
      }
    } else {
#pragma unroll
      for (int i = 0; i < 4; i++) {
        int kk = (t >> 6) + i * 4;
        Bs[kk][t & 63] = Bm[(size_t)(k0 + kk) * N + bn + (t & 63)];
      }
    }
    __syncthreads();
#pragma unroll
    for (int kk = 0; kk < 16; kk++) {
      float4 av = *(const float4*)&As[kk][ty * 4];
      float4 bv = *(const float4*)&Bs[kk][tx * 4];
      float a_[4] = {av.x, av.y, av.z, av.w};
      float b_[4] = {bv.x, bv.y, bv.z, bv.w};
#pragma unroll
      for (int i = 0; i < 4; i++)
#pragma unroll
        for (int j = 0; j < 4; j++) acc[i][j] += a_[i] * b_[j];
    }
    __syncthreads();
  }
#pragma unroll
  for (int i = 0; i < 4; i++) {
    int m = bm + ty * 4 + i;
    float tmp[4];
#pragma unroll
    for (int j = 0; j < 4; j++) {
      float x = acc[i][j];
      if (BIAS) x += bias[bn + tx * 4 + j];
      if (RELU) x = fmaxf(x, 0.f);
      tmp[j] = x;
    }
    float4 v;
    v.x = tmp[0]; v.y = tmp[1]; v.z = tmp[2]; v.w = tmp[3];
    *(float4*)&C[(size_t)m * N + bn + tx * 4] = v;
  }
}

// Fused scores+softmax+pool, ONLINE-softmax streaming version.
// Per (b, side): stream 64x512 f32 tile in 8 chunks of 8 atoms (16 KB),
// double-buffered global_load_lds. Tile is consumed (dot + pool) while the
// chunk sits in LDS -> single pass over HBM, no register-resident tile needed.
__global__ __launch_bounds__(512, 4) void k_atoms(const float* __restrict__ atomL, const float* __restrict__ atomR,
                                                  const float* __restrict__ uL, const float* __restrict__ uR,
                                                  const float* __restrict__ cL, const float* __restrict__ cR,
                                                  float* __restrict__ scoresL, float* __restrict__ scoresR,
                                                  float* __restrict__ pL, float* __restrict__ pR) {
  const int b = blockIdx.x, side = blockIdx.y;
  const float* __restrict__ atom = side ? atomR : atomL;
  const float* __restrict__ u = side ? uR : uL;
  const float cb = (side ? cR : cL)[b];
  float* __restrict__ scores = side ? scoresR : scoresL;
  float* __restrict__ p = side ? pR : pL;

  const int t = threadIdx.x, wave = t >> 6, lane = t & 63;

  __shared__ float buf[2][8 * 512];   // 2 x 16 KB chunk buffers
  __shared__ float s_all[64];
  __shared__ float e_lds[8];
  __shared__ float r_lds, z_lds;

  const char* gbase = (const char*)(atom + (size_t)b * 64 * H_);

  // prologue: stage chunk 0 into buf0
  {
    char* lb = (char*)&buf[0][0];
    gload_lds16(gbase + t * 16, lb + t * 16);
    gload_lds16(gbase + (512 + t) * 16, lb + (512 + t) * 16);
  }
  // u fragment: lane covers cols [4l,4l+4) and [256+4l, 256+4l+4)
  f32x4 u0 = *(const f32x4*)&u[(size_t)b * H_ + lane * 4];
  f32x4 u1 = *(const f32x4*)&u[(size_t)b * H_ + 256 + lane * 4];

  float pacc = 0.f;          // per-thread pooled column accumulator (col = t)
  float m_old = -FLT_MAX;    // live in wave 0 (uniform)
  float Z = 0.f;

  asm volatile("s_waitcnt vmcnt(0)" ::: "memory");
  BARRAW();

  int cur = 0;
#pragma unroll
  for (int c = 0; c < 8; c++) {
    // issue prefetch of next chunk into the other buffer
    if (c < 7) {
      const char* gb = gbase + (size_t)(c + 1) * 8 * 2048;
      char* lb = (char*)&buf[cur ^ 1][0];
      gload_lds16(gb + t * 16, lb + t * 16);
      gload_lds16(gb + (512 + t) * 16, lb + (512 + t) * 16);
    }
    // dots: wave w handles atom (c*8 + w)
    const float* bc = &buf[cur][0];
    {
      f32x4 a0 = *(const f32x4*)(bc + wave * 512 + lane * 4);
      f32x4 a1 = *(const f32x4*)(bc + wave * 512 + 256 + lane * 4);
      float dot = a0.x * u0.x + a0.y * u0.y + a0.z * u0.z + a0.w * u0.w +
                  a1.x * u1.x + a1.y * u1.y + a1.z * u1.z + a1.w * u1.w;
      dot = wred_sum(dot);
      if (lane == 0) s_all[c * 8 + wave] = dot + cb;
    }
    BARRAW();
    // online softmax update: wave 0 only
    if (wave == 0) {
      float val = (lane < 8) ? s_all[c * 8 + lane] : -FLT_MAX;
      float cmax = wred_max(val);
      float m_new = fmaxf(m_old, cmax);
      float r = expf(m_old - m_new);
      float e = (lane < 8) ? expf(val - m_new) : 0.f;
      float csum = wred_sum(e);
      Z = Z * r + csum;
      m_old = m_new;
      if (lane < 8) e_lds[lane] = e;
      if (lane == 0) { r_lds = r; z_lds = Z; }
    }
    BARRAW();
    // pool: thread t owns column t
    {
      float r = r_lds;
      float pp = pacc * r;
#pragma unroll
      for (int i = 0; i < 8; i++) pp += e_lds[i] * bc[i * 512 + t];
      pacc = pp;
    }
    asm volatile("s_waitcnt vmcnt(0)" ::: "memory");
    BARRAW();
    cur ^= 1;
  }

  float zf = z_lds;
  p[(size_t)b * H_ + t] = pacc / zf;
  if (wave == 0) scores[(size_t)b * 64 + lane] = expf(s_all[lane] - m_old) / zf;
}

// perturbation + bf16 pair assembly
__global__ __launch_bounds__(512) void k_pert(const float* __restrict__ lo, const float* __restrict__ ro,
                                              const float* __restrict__ noise,
                                              const float* __restrict__ pL, const float* __restrict__ pR,
                                              float* __restrict__ h_out, float* __restrict__ h_pert,
                                              bf16_t* __restrict__ pairbf) {
  const int b = blockIdx.x, t = threadIdx.x;
  float nv = noise[(size_t)b * H_ + t];
  float sq = nv * nv;
  sq = wred_sum(sq);
  __shared__ float red[8];
  if ((t & 63) == 0) red[t >> 6] = sq;
  __syncthreads();
  float tot = 0.f;
#pragma unroll
  for (int i = 0; i < 8; i++) tot += red[i];
  float nrm = fmaxf(sqrtf(tot), 1e-12f);
  float nn = nv / nrm * 0.1f;
  float h = ro[(size_t)b * H_ + t] * pL[(size_t)b * H_ + t];
  float tt = lo[(size_t)b * H_ + t] * pR[(size_t)b * H_ + t];
  float sh = (h > 0.f) ? 1.f : ((h < 0.f) ? -1.f : 0.f);
  float st = (tt > 0.f) ? 1.f : ((tt < 0.f) ? -1.f : 0.f);
  float hp = h + sh * nn;
  float tp = tt + st * nn;
  h_out[(size_t)b * H_ + t] = h;
  h_pert[(size_t)b * H_ + t] = hp;
  pairbf[(size_t)b * 1024 + t] = (bf16_t)hp;
  pairbf[(size_t)b * 1024 + 512 + t] = (bf16_t)tp;
}

// W1 [1024][2048] f32 -> W1t [2048][1024] bf16 (transpose + cast, LDS tiled)
__global__ __launch_bounds__(256) void k_w1t(const float* __restrict__ W1, bf16_t* __restrict__ W1t) {
  __shared__ float tile[32][33];
  const int bx = blockIdx.x;
  const int by = blockIdx.y;
  const int tx = threadIdx.x & 31, ty = threadIdx.x >> 5;
#pragma unroll
  for (int i = ty; i < 32; i += 8)
    tile[i][tx] = W1[(size_t)(by * 32 + i) * FFN_ + bx * 32 + tx];
  __syncthreads();
#pragma unroll
  for (int i = ty; i < 32; i += 8)
    W1t[(size_t)(bx * 32 + i) * 1024 + by * 32 + tx] = (bf16_t)tile[tx][i];
}

// FFN1 via MFMA bf16 (64x64 tile, XOR-swizzled source + matching swizzled read)
__global__ __launch_bounds__(256) void k_ffn1(const bf16_t* __restrict__ Abf, const bf16_t* __restrict__ Bt,
                                              const float* __restrict__ bias, float* __restrict__ C) {
  __shared__ bf16_t As[64 * 64];
  __shared__ bf16_t Bs[64 * 64];
  const int bm = blockIdx.x * 64, bn = blockIdx.y * 64;
  const int t = threadIdx.x;
  const int lane = t & 63, wave = t >> 6;
  const int wm = wave & 1, wn = wave >> 1;
  const int l15 = lane & 15, l4 = lane >> 4;
  f32x4 acc[2][2] = {{{0.f, 0.f, 0.f, 0.f}, {0.f, 0.f, 0.f, 0.f}},
                     {{0.f, 0.f, 0.f, 0.f}, {0.f, 0.f, 0.f, 0.f}}};

  for (int k0 = 0; k0 < 1024; k0 += 64) {
#pragma unroll
    for (int r = 0; r < 2; r++) {
      const int off = (r * 256 + t) * 16;
      const int row = off >> 7;
      const int g = (off >> 4) & 7;
      const int scb = ((g ^ (row & 7)) << 4);
      gload_lds16((const char*)Abf + (size_t)(bm + row) * 2048 + k0 * 2 + scb, (char*)As + off);
      gload_lds16((const char*)Bt + (size_t)(bn + row) * 2048 + k0 * 2 + scb, (char*)Bs + off);
    }
    __syncthreads();
#pragma unroll
    for (int ks = 0; ks < 2; ks++) {
      const int ar0 = wm * 32 + l15, ar1 = ar0 + 16;
      const int br0 = wn * 32 + l15, br1 = br0 + 16;
      const int gA = ks * 4 + l4;
      bf16x8 a0 = *(const bf16x8*)((const char*)As + ar0 * 128 + ((gA ^ (ar0 & 7)) << 4));
      bf16x8 a1 = *(const bf16x8*)((const char*)As + ar1 * 128 + ((gA ^ (ar1 & 7)) << 4));
      bf16x8 b0 = *(const bf16x8*)((const char*)Bs + br0 * 128 + ((gA ^ (br0 & 7)) << 4));
      bf16x8 b1 = *(const bf16x8*)((const char*)Bs + br1 * 128 + ((gA ^ (br1 & 7)) << 4));
      acc[0][0] = __builtin_amdgcn_mfma_f32_16x16x32_bf16(a0, b0, acc[0][0], 0, 0, 0);
      acc[0][1] = __builtin_amdgcn_mfma_f32_16x16x32_bf16(a0, b1, acc[0][1], 0, 0, 0);
      acc[1][0] = __builtin_amdgcn_mfma_f32_16x16x32_bf16(a1, b0, acc[1][0], 0, 0, 0);
      acc[1][1] = __builtin_amdgcn_mfma_f32_16x16x32_bf16(a1, b1, acc[1][1], 0, 0, 0);
    }
    __syncthreads();
  }
#pragma unroll
  for (int mi = 0; mi < 2; mi++)
#pragma unroll
    for (int nj = 0; nj < 2; nj++)
#pragma unroll
      for (int r = 0; r < 4; r++) {
        const int m = bm + wm * 32 + mi * 16 + l4 * 4 + r;
        const int n = bn + wn * 32 + nj * 16 + l15;
        float v = acc[mi][nj][r] + bias[n];
        C[(size_t)m * FFN_ + n] = fmaxf(v, 0.f);
      }
}

__global__ void k_w2t(const float* __restrict__ W2, float* __restrict__ W2t) {
  int idx = blockIdx.x * 256 + threadIdx.x;
  if (idx < OUT_ * FFN_) {
    int n = idx / FFN_, k = idx % FFN_;
    W2t[idx] = W2[(size_t)k * OUT_ + n];
  }
}

__global__ __launch_bounds__(256) void k_ffn2(const float* __restrict__ hid, const float* __restrict__ W2t,
                                              const float* __restrict__ b2, float* __restrict__ out) {
  const int b0 = blockIdx.x * 2;
  const int t = threadIdx.x, wave = t >> 6, lane = t & 63;
  float4 h0[8], h1[8];
  const float* r0 = hid + (size_t)b0 * FFN_;
#pragma unroll
  for (int j = 0; j < 8; j++) {
    h0[j] = *(const float4*)&r0[lane * 4 + j * 256];
    h1[j] = *(const float4*)&r0[FFN_ + lane * 4 + j * 256];
  }
  for (int n = wave; n < OUT_; n += 4) {
    const float* wrow = W2t + (size_t)n * FFN_;
    float s0 = 0.f, s1 = 0.f;
#pragma unroll
    for (int j = 0; j < 8; j++) {
      float4 w4 = *(const float4*)&wrow[lane * 4 + j * 256];
      s0 += w4.x * h0[j].x + w4.y * h0[j].y + w4.z * h0[j].z + w4.w * h0[j].w;
      s1 += w4.x * h1[j].x + w4.y * h1[j].y + w4.z * h1[j].z + w4.w * h1[j].w;
    }
    s0 = wred_sum(s0);
    s1 = wred_sum(s1);
    if (lane == 0) {
      out[(size_t)b0 * OUT_ + n] = s0 + b2[n];
      out[(size_t)(b0 + 1) * OUT_ + n] = s1 + b2[n];
    }
  }
}

extern "C" void kernel_launch(void* const* d_in, const int* in_sizes, int n_in,
                              void* d_out, int out_size, void* d_ws, size_t ws_size,
                              hipStream_t stream) {
  const float* lo = (const float*)d_in[0];
  const float* ro = (const float*)d_in[1];
  const float* la = (const float*)d_in[2];
  const float* ra = (const float*)d_in[3];
  const float* noise = (const float*)d_in[6];
  const float* w_i_w = (const float*)d_in[7];
  const float* w_i_b = (const float*)d_in[8];
  const float* prj_w = (const float*)d_in[9];
  const float* prj_b = (const float*)d_in[10];
  const float* W1 = (const float*)d_in[11];
  const float* b1 = (const float*)d_in[12];
  const float* W2 = (const float*)d_in[13];
  const float* b2 = (const float*)d_in[14];

  float* out = (float*)d_out;
  float* o_logits = out;                  // [1024,86]
  float* o_hout  = out + 88064;           // [1024,512]
  float* o_hpert = o_hout + 524288;       // [1024,512]
  float* o_ls    = o_hpert + 524288;      // [65536]
  float* o_rs    = o_ls + 65536;          // [65536]
  float* o_lo    = o_rs + 65536;          // [1024,512]
  float* o_ro    = o_lo + 524288;         // [1024,512]

  float* ws = (float*)d_ws;
  float* Mt   = ws; ws += 512 * 512;
  float* uL   = ws; ws += B_ * H_;
  float* uR   = ws; ws += B_ * H_;
  float* pL   = ws; ws += B_ * H_;
  float* pR   = ws; ws += B_ * H_;
  float* hid  = ws; ws += B_ * FFN_;
  float* W2t  = ws; ws += OUT_ * FFN_;
  bf16_t* pairbf = (bf16_t*)ws; ws += B_ * 1024 / 2;
  bf16_t* W1t    = (bf16_t*)ws; ws += FFN_ * 1024 / 2;
  float* dv   = ws; ws += 512;
  float* ev   = ws; ws += 512;
  float* cL   = ws; ws += 1024;
  float* cR   = ws; ws += 1024;
  float* c0   = ws; ws += 4;

  k_prep<<<1025, 64, 0, stream>>>(w_i_w, w_i_b, prj_w, prj_b, dv, ev, c0);
  gemm64<true, false, false><<<dim3(8, 8), 256, 0, stream>>>(w_i_w, prj_w, nullptr, Mt, 512, 512, 512);
  gemm64<true, true, false><<<dim3(16, 8), 256, 0, stream>>>(ro, Mt, dv, uL, 1024, 512, 512);
  gemm64<true, true, false><<<dim3(16, 8), 256, 0, stream>>>(lo, Mt, dv, uR, 1024, 512, 512);
  k_cvec<<<dim3(1024, 2), 64, 0, stream>>>(ro, lo, ev, c0, cL, cR);
  k_w1t<<<dim3(64, 32), 256, 0, stream>>>(W1, W1t);
  k_atoms<<<dim3(1024, 2), 512, 0, stream>>>(la, ra, uL, uR, cL, cR, o_ls, o_rs, pL, pR);
  k_pert<<<1024, 512, 0, stream>>>(lo, ro, noise, pL, pR, o_hout, o_hpert, pairbf);
  k_ffn1<<<dim3(16, 32), 256, 0, stream>>>(pairbf, W1t, b1, hid);
  k_w2t<<<688, 256, 0, stream>>>(W2, W2t);
  k_ffn2<<<512, 256, 0, stream>>>(hid, W2t, b2, o_logits);
  hipMemcpyAsync(o_lo, lo, (size_t)B_ * H_ * 4, hipMemcpyDeviceToDevice, stream);
  hipMemcpyAsync(o_ro, ro, (size_t)B_ * H_ * 4, hipMemcpyDeviceToDevice, stream);
}

// Round 4
// 173.279 us; speedup vs baseline: 1.3885x; 1.3885x over previous
//
#include <hip/hip_runtime.h>
#include <hip/hip_bf16.h>
#include <float.h>

#define B_ 1024
#define H_ 512
#define N_ (B_ * 64)
#define FFN_ 2048
#define OUT_ 86

typedef __bf16 bf16_t;
typedef __attribute__((ext_vector_type(8))) __bf16 bf16x8;
typedef __attribute__((ext_vector_type(4))) float f32x4;

__device__ __forceinline__ float wred_sum(float v) {
#pragma unroll
  for (int m = 32; m; m >>= 1) v += __shfl_xor(v, m);
  return v;
}

__device__ __forceinline__ void gload_lds16(const void* g, void* l) {
  __builtin_amdgcn_global_load_lds((const __attribute__((address_space(1))) unsigned int*)g,
                                   (__attribute__((address_space(3))) unsigned int*)l, 16, 0, 0);
}

// ev[j] = sum_h prj_w[j][h]*w_i_b[h]; c0 = w_i_b . prj_b   (dv no longer needed)
__global__ void k_prep(const float* __restrict__ w_i_b,
                       const float* __restrict__ prj_w, const float* __restrict__ prj_b,
                       float* __restrict__ ev, float* __restrict__ c0) {
  int b = blockIdx.x, l = threadIdx.x;
  float s = 0.f;
  if (b < 512) {
    for (int h = l; h < H_; h += 64) s += prj_w[b * H_ + h] * w_i_b[h];
    s = wred_sum(s);
    if (l == 0) ev[b] = s;
  } else {
    for (int h = l; h < H_; h += 64) s += w_i_b[h] * prj_b[h];
    s = wred_sum(s);
    if (l == 0) c0[0] = s;
  }
}

__global__ void k_cvec(const float* __restrict__ ro, const float* __restrict__ lo,
                       const float* __restrict__ ev, const float* __restrict__ c0,
                       float* __restrict__ cL, float* __restrict__ cR) {
  int b = blockIdx.x, side = blockIdx.y, l = threadIdx.x;
  const float* x = side ? lo : ro;
  float s = 0.f;
  for (int j = l; j < H_; j += 64) s += x[b * H_ + j] * ev[j];
  s = wred_sum(s);
  if (l == 0) (side ? cR : cL)[b] = s + c0[0];
}

// f32 tiled GEMM, 64x64 tile, BK=16, 4x4 accum. A split across two row blocks
// (A1 rows [0,M1), A2 rows [M1,M)) so [ro;lo] never gets materialized.
// BT=true: B is [N][K] row-major (NT). BT=false: B is [K][N] (NN).
template <bool BT, bool BIAS>
__global__ __launch_bounds__(256) void gemm64(const float* __restrict__ A1, const float* __restrict__ A2,
                                              int M1, const float* __restrict__ Bm,
                                              const float* __restrict__ bias, float* __restrict__ C,
                                              int N, int K) {
  __shared__ float As[16][68];
  __shared__ float Bs[16][68];
  const int bm = blockIdx.x * 64, bn = blockIdx.y * 64;
  const float* __restrict__ A = (bm < M1) ? (A1 + (size_t)bm * K) : (A2 + (size_t)(bm - M1) * K);
  const int t = threadIdx.x;
  const int tx = t & 15, ty = t >> 4;
  float acc[4][4] = {};
  for (int k0 = 0; k0 < K; k0 += 16) {
#pragma unroll
    for (int i = 0; i < 4; i++) {
      int m = (t >> 4) + i * 16;
      As[t & 15][m] = A[(size_t)m * K + k0 + (t & 15)];
    }
    if (BT) {
#pragma unroll
      for (int i = 0; i < 4; i++) {
        int n = (t >> 4) + i * 16;
        Bs[t & 15][n] = Bm[(size_t)(bn + n) * K + k0 + (t & 15)];
      }
    } else {
#pragma unroll
      for (int i = 0; i < 4; i++) {
        int kk = (t >> 6) + i * 4;
        Bs[kk][t & 63] = Bm[(size_t)(k0 + kk) * N + bn + (t & 63)];
      }
    }
    __syncthreads();
#pragma unroll
    for (int kk = 0; kk < 16; kk++) {
      float4 av = *(const float4*)&As[kk][ty * 4];
      float4 bv = *(const float4*)&Bs[kk][tx * 4];
      float a_[4] = {av.x, av.y, av.z, av.w};
      float b_[4] = {bv.x, bv.y, bv.z, bv.w};
#pragma unroll
      for (int i = 0; i < 4; i++)
#pragma unroll
        for (int j = 0; j < 4; j++) acc[i][j] += a_[i] * b_[j];
    }
    __syncthreads();
  }
#pragma unroll
  for (int i = 0; i < 4; i++) {
    int m = bm + ty * 4 + i;
    float tmp[4];
#pragma unroll
    for (int j = 0; j < 4; j++) {
      float x = acc[i][j];
      if (BIAS) x += bias[bn + tx * 4 + j];
      tmp[j] = x;
    }
    float4 v;
    v.x = tmp[0]; v.y = tmp[1]; v.z = tmp[2]; v.w = tmp[3];
    *(float4*)&C[(size_t)m * N + bn + tx * 4] = v;
  }
}

// Fused scores+softmax+pool, WAVE-AUTONOMOUS online-softmax version.
// One wave per (b, side). Lane owns cols 8l..8l+8. No LDS, no barriers.
// 8 chunks of 8 atoms: a[8][8] in regs, 8 independent shfl-reduce dot chains,
// wave-uniform online (m,z) update, pool accumulates in q[8] with rescale.
__global__ __launch_bounds__(256, 2) void k_atoms2(const float* __restrict__ atomL, const float* __restrict__ atomR,
                                                   const float* __restrict__ uLR,
                                                   const float* __restrict__ cL, const float* __restrict__ cR,
                                                   float* __restrict__ scoresL, float* __restrict__ scoresR,
                                                   float* __restrict__ pL, float* __restrict__ pR) {
  const int gw = blockIdx.x * 4 + (threadIdx.x >> 6);  // 0..2047
  const int side = gw >> 10;
  const int b = gw & 1023;
  const int lane = threadIdx.x & 63;

  const float* __restrict__ atom = side ? atomR : atomL;
  const float cb = (side ? cR : cL)[b];
  float* __restrict__ scores = side ? scoresR : scoresL;
  float* __restrict__ p = side ? pR : pL;

  const float* __restrict__ u = uLR + (size_t)gw * H_;
  float ur[8];
  *(f32x4*)&ur[0] = *(const f32x4*)&u[lane * 8];
  *(f32x4*)&ur[4] = *(const f32x4*)&u[lane * 8 + 4];

  const float* __restrict__ base = atom + (size_t)b * 64 * H_ + lane * 8;

  float q[8] = {};
  float m_run = -FLT_MAX, z_run = 0.f;
  float myraw = 0.f;

#pragma unroll
  for (int c = 0; c < 8; c++) {
    float a[8][8];
    // 16 independent 16B loads
#pragma unroll
    for (int i = 0; i < 8; i++) {
      const float* rp = base + (size_t)(c * 8 + i) * H_;
      *(f32x4*)&a[i][0] = *(const f32x4*)rp;
      *(f32x4*)&a[i][4] = *(const f32x4*)(rp + 4);
    }
    float d[8];
#pragma unroll
    for (int i = 0; i < 8; i++) {
      float s = 0.f;
#pragma unroll
      for (int j = 0; j < 8; j++) s += a[i][j] * ur[j];
      d[i] = s;
    }
    // 8 independent butterfly reductions (interleaved by scheduler)
#pragma unroll
    for (int i = 0; i < 8; i++) d[i] = wred_sum(d[i]) + cb;
    // capture raw score for this lane's atom (static-index cndmask chain)
#pragma unroll
    for (int i = 0; i < 8; i++) myraw = (lane == c * 8 + i) ? d[i] : myraw;
    // wave-uniform online softmax update
    float mc = d[0];
#pragma unroll
    for (int i = 1; i < 8; i++) mc = fmaxf(mc, d[i]);
    float m_new = fmaxf(m_run, mc);
    float r = __expf(m_run - m_new);
    float e[8];
    float zc = 0.f;
#pragma unroll
    for (int i = 0; i < 8; i++) { e[i] = __expf(d[i] - m_new); zc += e[i]; }
    z_run = z_run * r + zc;
    m_run = m_new;
    // pool with rescale
#pragma unroll
    for (int j = 0; j < 8; j++) q[j] *= r;
#pragma unroll
    for (int i = 0; i < 8; i++)
#pragma unroll
      for (int j = 0; j < 8; j++) q[j] += e[i] * a[i][j];
  }

  const float zinv = 1.f / z_run;
  float outp[8];
#pragma unroll
  for (int j = 0; j < 8; j++) outp[j] = q[j] * zinv;
  float* pd = p + (size_t)b * H_ + lane * 8;
  *(f32x4*)&pd[0] = *(const f32x4*)&outp[0];
  *(f32x4*)&pd[4] = *(const f32x4*)&outp[4];
  scores[(size_t)b * 64 + lane] = __expf(myraw - m_run) * zinv;
}

// perturbation + bf16 pair assembly
__global__ __launch_bounds__(512) void k_pert(const float* __restrict__ lo, const float* __restrict__ ro,
                                              const float* __restrict__ noise,
                                              const float* __restrict__ pL, const float* __restrict__ pR,
                                              float* __restrict__ h_out, float* __restrict__ h_pert,
                                              bf16_t* __restrict__ pairbf) {
  const int b = blockIdx.x, t = threadIdx.x;
  float nv = noise[(size_t)b * H_ + t];
  float sq = nv * nv;
  sq = wred_sum(sq);
  __shared__ float red[8];
  if ((t & 63) == 0) red[t >> 6] = sq;
  __syncthreads();
  float tot = 0.f;
#pragma unroll
  for (int i = 0; i < 8; i++) tot += red[i];
  float nrm = fmaxf(sqrtf(tot), 1e-12f);
  float nn = nv / nrm * 0.1f;
  float h = ro[(size_t)b * H_ + t] * pL[(size_t)b * H_ + t];
  float tt = lo[(size_t)b * H_ + t] * pR[(size_t)b * H_ + t];
  float sh = (h > 0.f) ? 1.f : ((h < 0.f) ? -1.f : 0.f);
  float st = (tt > 0.f) ? 1.f : ((tt < 0.f) ? -1.f : 0.f);
  float hp = h + sh * nn;
  float tp = tt + st * nn;
  h_out[(size_t)b * H_ + t] = h;
  h_pert[(size_t)b * H_ + t] = hp;
  pairbf[(size_t)b * 1024 + t] = (bf16_t)hp;
  pairbf[(size_t)b * 1024 + 512 + t] = (bf16_t)tp;
}

// W1 [1024][2048] f32 -> W1t [2048][1024] bf16 (transpose + cast, LDS tiled)
__global__ __launch_bounds__(256) void k_w1t(const float* __restrict__ W1, bf16_t* __restrict__ W1t) {
  __shared__ float tile[32][33];
  const int bx = blockIdx.x;
  const int by = blockIdx.y;
  const int tx = threadIdx.x & 31, ty = threadIdx.x >> 5;
#pragma unroll
  for (int i = ty; i < 32; i += 8)
    tile[i][tx] = W1[(size_t)(by * 32 + i) * FFN_ + bx * 32 + tx];
  __syncthreads();
#pragma unroll
  for (int i = ty; i < 32; i += 8)
    W1t[(size_t)(bx * 32 + i) * 1024 + by * 32 + tx] = (bf16_t)tile[tx][i];
}

// FFN1 via MFMA bf16 (64x64 tile, XOR-swizzled source + matching swizzled read)
__global__ __launch_bounds__(256) void k_ffn1(const bf16_t* __restrict__ Abf, const bf16_t* __restrict__ Bt,
                                              const float* __restrict__ bias, float* __restrict__ C) {
  __shared__ bf16_t As[64 * 64];
  __shared__ bf16_t Bs[64 * 64];
  const int bm = blockIdx.x * 64, bn = blockIdx.y * 64;
  const int t = threadIdx.x;
  const int lane = t & 63, wave = t >> 6;
  const int wm = wave & 1, wn = wave >> 1;
  const int l15 = lane & 15, l4 = lane >> 4;
  f32x4 acc[2][2] = {{{0.f, 0.f, 0.f, 0.f}, {0.f, 0.f, 0.f, 0.f}},
                     {{0.f, 0.f, 0.f, 0.f}, {0.f, 0.f, 0.f, 0.f}}};

  for (int k0 = 0; k0 < 1024; k0 += 64) {
#pragma unroll
    for (int r = 0; r < 2; r++) {
      const int off = (r * 256 + t) * 16;
      const int row = off >> 7;
      const int g = (off >> 4) & 7;
      const int scb = ((g ^ (row & 7)) << 4);
      gload_lds16((const char*)Abf + (size_t)(bm + row) * 2048 + k0 * 2 + scb, (char*)As + off);
      gload_lds16((const char*)Bt + (size_t)(bn + row) * 2048 + k0 * 2 + scb, (char*)Bs + off);
    }
    __syncthreads();
#pragma unroll
    for (int ks = 0; ks < 2; ks++) {
      const int ar0 = wm * 32 + l15, ar1 = ar0 + 16;
      const int br0 = wn * 32 + l15, br1 = br0 + 16;
      const int gA = ks * 4 + l4;
      bf16x8 a0 = *(const bf16x8*)((const char*)As + ar0 * 128 + ((gA ^ (ar0 & 7)) << 4));
      bf16x8 a1 = *(const bf16x8*)((const char*)As + ar1 * 128 + ((gA ^ (ar1 & 7)) << 4));
      bf16x8 b0 = *(const bf16x8*)((const char*)Bs + br0 * 128 + ((gA ^ (br0 & 7)) << 4));
      bf16x8 b1 = *(const bf16x8*)((const char*)Bs + br1 * 128 + ((gA ^ (br1 & 7)) << 4));
      acc[0][0] = __builtin_amdgcn_mfma_f32_16x16x32_bf16(a0, b0, acc[0][0], 0, 0, 0);
      acc[0][1] = __builtin_amdgcn_mfma_f32_16x16x32_bf16(a0, b1, acc[0][1], 0, 0, 0);
      acc[1][0] = __builtin_amdgcn_mfma_f32_16x16x32_bf16(a1, b0, acc[1][0], 0, 0, 0);
      acc[1][1] = __builtin_amdgcn_mfma_f32_16x16x32_bf16(a1, b1, acc[1][1], 0, 0, 0);
    }
    __syncthreads();
  }
#pragma unroll
  for (int mi = 0; mi < 2; mi++)
#pragma unroll
    for (int nj = 0; nj < 2; nj++)
#pragma unroll
      for (int r = 0; r < 4; r++) {
        const int m = bm + wm * 32 + mi * 16 + l4 * 4 + r;
        const int n = bn + wn * 32 + nj * 16 + l15;
        float v = acc[mi][nj][r] + bias[n];
        C[(size_t)m * FFN_ + n] = fmaxf(v, 0.f);
      }
}

__global__ void k_w2t(const float* __restrict__ W2, float* __restrict__ W2t) {
  int idx = blockIdx.x * 256 + threadIdx.x;
  if (idx < OUT_ * FFN_) {
    int n = idx / FFN_, k = idx % FFN_;
    W2t[idx] = W2[(size_t)k * OUT_ + n];
  }
}

__global__ __launch_bounds__(256) void k_ffn2(const float* __restrict__ hid, const float* __restrict__ W2t,
                                              const float* __restrict__ b2, float* __restrict__ out) {
  const int b0 = blockIdx.x * 2;
  const int t = threadIdx.x, wave = t >> 6, lane = t & 63;
  float4 h0[8], h1[8];
  const float* r0 = hid + (size_t)b0 * FFN_;
#pragma unroll
  for (int j = 0; j < 8; j++) {
    h0[j] = *(const float4*)&r0[lane * 4 + j * 256];
    h1[j] = *(const float4*)&r0[FFN_ + lane * 4 + j * 256];
  }
  for (int n = wave; n < OUT_; n += 4) {
    const float* wrow = W2t + (size_t)n * FFN_;
    float s0 = 0.f, s1 = 0.f;
#pragma unroll
    for (int j = 0; j < 8; j++) {
      float4 w4 = *(const float4*)&wrow[lane * 4 + j * 256];
      s0 += w4.x * h0[j].x + w4.y * h0[j].y + w4.z * h0[j].z + w4.w * h0[j].w;
      s1 += w4.x * h1[j].x + w4.y * h1[j].y + w4.z * h1[j].z + w4.w * h1[j].w;
    }
    s0 = wred_sum(s0);
    s1 = wred_sum(s1);
    if (lane == 0) {
      out[(size_t)b0 * OUT_ + n] = s0 + b2[n];
      out[(size_t)(b0 + 1) * OUT_ + n] = s1 + b2[n];
    }
  }
}

extern "C" void kernel_launch(void* const* d_in, const int* in_sizes, int n_in,
                              void* d_out, int out_size, void* d_ws, size_t ws_size,
                              hipStream_t stream) {
  const float* lo = (const float*)d_in[0];
  const float* ro = (const float*)d_in[1];
  const float* la = (const float*)d_in[2];
  const float* ra = (const float*)d_in[3];
  const float* noise = (const float*)d_in[6];
  const float* w_i_w = (const float*)d_in[7];
  const float* w_i_b = (const float*)d_in[8];
  const float* prj_w = (const float*)d_in[9];
  const float* prj_b = (const float*)d_in[10];
  const float* W1 = (const float*)d_in[11];
  const float* b1 = (const float*)d_in[12];
  const float* W2 = (const float*)d_in[13];
  const float* b2 = (const float*)d_in[14];

  float* out = (float*)d_out;
  float* o_logits = out;                  // [1024,86]
  float* o_hout  = out + 88064;           // [1024,512]
  float* o_hpert = o_hout + 524288;       // [1024,512]
  float* o_ls    = o_hpert + 524288;      // [65536]
  float* o_rs    = o_ls + 65536;          // [65536]
  float* o_lo    = o_rs + 65536;          // [1024,512]
  float* o_ro    = o_lo + 524288;         // [1024,512]

  float* ws = (float*)d_ws;
  float* T    = ws; ws += 2048 * 512;     // [ro;lo] @ prj_w + prj_b
  float* uLR  = ws; ws += 2048 * 512;     // T @ w_i_w^T  (rows 0-1023 = uL, 1024+ = uR)
  float* pL   = ws; ws += B_ * H_;
  float* pR   = ws; ws += B_ * H_;
  float* hid  = ws; ws += B_ * FFN_;
  float* W2t  = ws; ws += OUT_ * FFN_;
  bf16_t* pairbf = (bf16_t*)ws; ws += B_ * 1024 / 2;
  bf16_t* W1t    = (bf16_t*)ws; ws += FFN_ * 1024 / 2;
  float* ev   = ws; ws += 512;
  float* cL   = ws; ws += 1024;
  float* cR   = ws; ws += 1024;
  float* c0   = ws; ws += 4;

  k_prep<<<513, 64, 0, stream>>>(w_i_b, prj_w, prj_b, ev, c0);
  // T = [ro;lo] @ prj_w + prj_b   (NN, 2048x512x512, full-GPU grid)
  gemm64<false, true><<<dim3(32, 8), 256, 0, stream>>>(ro, lo, 1024, prj_w, prj_b, T, 512, 512);
  // uLR = T @ w_i_w^T             (NT, 2048x512x512; Mt eliminated by associativity)
  gemm64<true, false><<<dim3(32, 8), 256, 0, stream>>>(T, T, 1 << 30, w_i_w, nullptr, uLR, 512, 512);
  k_cvec<<<dim3(1024, 2), 64, 0, stream>>>(ro, lo, ev, c0, cL, cR);
  k_w1t<<<dim3(64, 32), 256, 0, stream>>>(W1, W1t);
  k_atoms2<<<512, 256, 0, stream>>>(la, ra, uLR, cL, cR, o_ls, o_rs, pL, pR);
  k_pert<<<1024, 512, 0, stream>>>(lo, ro, noise, pL, pR, o_hout, o_hpert, pairbf);
  k_ffn1<<<dim3(16, 32), 256, 0, stream>>>(pairbf, W1t, b1, hid);
  k_w2t<<<688, 256, 0, stream>>>(W2, W2t);
  k_ffn2<<<512, 256, 0, stream>>>(hid, W2t, b2, o_logits);
  hipMemcpyAsync(o_lo, lo, (size_t)B_ * H_ * 4, hipMemcpyDeviceToDevice, stream);
  hipMemcpyAsync(o_ro, ro, (size_t)B_ * H_ * 4, hipMemcpyDeviceToDevice, stream);
}